// Round 1
// baseline (356.875 us; speedup 1.0000x reference)
//
#include <hip/hip_runtime.h>
#include <math.h>

// Problem constants
#define NN   1024
#define PP   4
#define SS   12
#define MM   64
#define KK   16
#define LL   8
#define MKK  80          // M + K
#define NSYM 13          // S + 1
#define SMK  1040        // NSYM * MKK
#define NITEMS 832       // NSYM * MM

// Output layout (float element offsets in d_out)
#define OFF_PILOT  0
#define OFF_SIG    524288      // N*P*1*M*2
#define OFF_H      6815744     // + N*P*S*M*2
#define OFF_SCALAR 7340032     // + N*P*M*2

#define NOISE_PWR   1.5625e-4f            // PWR/(M*10^(0.1*SNR)) = 1/6400
#define NOISE_SCALE 8.8388347648318447e-3f // sqrt(NOISE_PWR/2)

__device__ __forceinline__ float2 cmul(float2 a, float2 b) {
    return make_float2(a.x*b.x - a.y*b.y, a.x*b.y + a.y*b.x);
}
__device__ __forceinline__ float2 cmul_conj(float2 a, float2 b) {
    // a * conj(b)
    return make_float2(a.x*b.x + a.y*b.y, a.y*b.x - a.x*b.y);
}

__global__ __launch_bounds__(256) void ofdm_kernel(
    const float2* __restrict__ x,          // (NP, S, M)
    const float2* __restrict__ pilot_raw,  // (NP, M)
    const float2* __restrict__ cof_unit,   // (NP, L)
    const float2* __restrict__ noise_unit, // (NP, NSYM, MKK)
    float2* __restrict__ out_pilot,        // (NP, M)
    float2* __restrict__ out_sig,          // (NP, S, M)
    float2* __restrict__ out_H,            // (NP, M)
    float*  __restrict__ out_scalar)
{
    const int b   = blockIdx.x;
    const int tid = threadIdx.x;

    __shared__ float2 tw[64];       // exp(-2*pi*i*j/64)
    __shared__ float2 buf[NITEMS];  // freq-domain staging, later post-channel z
    __shared__ float2 sig[SMK];     // serialized time signal with CP
    __shared__ float2 cofs[LL];
    __shared__ float  alpha_s;

    const float2* xb = x          + (size_t)b * (SS*MM);
    const float2* pb = pilot_raw  + (size_t)b * MM;
    const float2* cb = cof_unit   + (size_t)b * LL;
    const float2* nb = noise_unit + (size_t)b * (NSYM*MKK);

    // --- twiddles + pilot power (wave 0), channel taps (wave 1) ---
    if (tid < 64) {
        float ang = -6.2831853071795864769f * (float)tid * (1.0f/64.0f);
        float s, c;
        sincosf(ang, &s, &c);
        tw[tid] = make_float2(c, s);

        float2 pr = pb[tid];
        float ss = pr.x*pr.x + pr.y*pr.y;
        #pragma unroll
        for (int off = 32; off > 0; off >>= 1)
            ss += __shfl_down(ss, off);
        if (tid == 0) alpha_s = sqrtf(64.0f / ss);   // sqrt(0.5/(sumsq/128))
    } else if (tid >= 64 && tid < 64 + LL) {
        int l = tid - 64;
        float psum = 0.0f;
        #pragma unroll
        for (int j = 0; j < LL; ++j) psum += __expf(-(float)j * 0.25f);
        float prof = __expf(-(float)l * 0.25f) / psum;
        float sc = sqrtf(prof * 0.5f);
        float2 u = cb[l];
        cofs[l] = make_float2(sc*u.x, sc*u.y);
    }
    __syncthreads();

    // --- H_true = FFT64 of zero-padded taps ---
    if (tid < 64) {
        float2 h = make_float2(0.f, 0.f);
        #pragma unroll
        for (int l = 0; l < LL; ++l) {
            float2 t = tw[(l*tid) & 63];
            float2 c = cofs[l];
            h.x += c.x*t.x - c.y*t.y;
            h.y += c.x*t.y + c.y*t.x;
        }
        out_H[(size_t)b*64 + tid] = h;
    }

    // --- stage frequency-domain symbols (pilot scaled by alpha) ---
    {
        float a = alpha_s;
        for (int i = tid; i < NITEMS; i += 256) {
            int s = i >> 6, k = i & 63;
            float2 v;
            if (s == 0) { float2 p = pb[k]; v = make_float2(a*p.x, a*p.y); }
            else        { v = xb[i - 64]; }
            buf[i] = v;
        }
    }
    __syncthreads();

    // --- IFFT64 each symbol, write into serialized signal with CP ---
    for (int i = tid; i < NITEMS; i += 256) {
        int s = i >> 6, n = i & 63;
        const float2* X = &buf[s << 6];
        float2 acc = make_float2(0.f, 0.f);
        #pragma unroll
        for (int k = 0; k < 64; ++k) {
            float2 t = tw[(n*k) & 63];
            float2 v = X[k];
            acc.x += v.x*t.x + v.y*t.y;   // v * conj(t)
            acc.y += v.y*t.x - v.x*t.y;
        }
        acc.x *= (1.0f/64.0f);
        acc.y *= (1.0f/64.0f);
        sig[s*MKK + KK + n] = acc;
        if (n >= MM - KK) sig[s*MKK + n - (MM - KK)] = acc;   // cyclic prefix
    }
    __syncthreads();

    // --- 8-tap FIR channel + AWGN, CP stripped (only positions K..MK-1) ---
    for (int i = tid; i < NITEMS; i += 256) {
        int s = i >> 6, m = i & 63;
        int pos = s*MKK + KK + m;
        float2 acc = make_float2(0.f, 0.f);
        #pragma unroll
        for (int t = 0; t < LL; ++t) {
            float2 c = cofs[t];
            float2 v = sig[pos - t];
            acc.x += c.x*v.x - c.y*v.y;
            acc.y += c.x*v.y + c.y*v.x;
        }
        float2 nu = nb[pos];
        acc.x += NOISE_SCALE * nu.x;
        acc.y += NOISE_SCALE * nu.y;
        buf[i] = acc;   // reuse buf as z (freq staging no longer needed)
    }
    __syncthreads();

    // --- FFT64 back to frequency domain, write outputs ---
    for (int i = tid; i < NITEMS; i += 256) {
        int s = i >> 6, k = i & 63;
        const float2* Z = &buf[s << 6];
        float2 acc = make_float2(0.f, 0.f);
        #pragma unroll
        for (int m = 0; m < 64; ++m) {
            float2 t = tw[(m*k) & 63];
            float2 v = Z[m];
            acc.x += v.x*t.x - v.y*t.y;
            acc.y += v.x*t.y + v.y*t.x;
        }
        if (s == 0) out_pilot[(size_t)b*64 + k] = acc;
        else        out_sig[(size_t)b*(SS*64) + (i - 64)] = acc;
    }

    if (b == 0 && tid == 0) out_scalar[0] = NOISE_PWR;
}

extern "C" void kernel_launch(void* const* d_in, const int* in_sizes, int n_in,
                              void* d_out, int out_size, void* d_ws, size_t ws_size,
                              hipStream_t stream) {
    const float2* x  = (const float2*)d_in[0];
    const float2* pr = (const float2*)d_in[1];
    const float2* cu = (const float2*)d_in[2];
    const float2* nu = (const float2*)d_in[3];

    float* out = (float*)d_out;
    float2* out_pilot = (float2*)(out + OFF_PILOT);
    float2* out_sig   = (float2*)(out + OFF_SIG);
    float2* out_H     = (float2*)(out + OFF_H);
    float*  out_sc    = out + OFF_SCALAR;

    ofdm_kernel<<<dim3(NN*PP), dim3(256), 0, stream>>>(
        x, pr, cu, nu, out_pilot, out_sig, out_H, out_sc);
}

// Round 2
// 127.777 us; speedup vs baseline: 2.7930x; 2.7930x over previous
//
#include <hip/hip_runtime.h>
#include <math.h>

// Problem constants
#define NN   1024
#define PP   4
#define SS   12
#define MM   64
#define KK   16
#define LL   8
#define MKK  80          // M + K
#define NSYM 13          // S + 1
#define SMK  1040        // NSYM * MKK
#define NITEMS 832       // NSYM * MM

// Output layout (float element offsets in d_out)
#define OFF_PILOT  0
#define OFF_SIG    524288      // N*P*1*M*2
#define OFF_H      6815744     // + N*P*S*M*2
#define OFF_SCALAR 7340032     // + N*P*M*2

#define NOISE_PWR   1.5625e-4f             // PWR/(M*10^(0.1*SNR)) = 1/6400
#define NOISE_SCALE 8.8388347648318447e-3f // sqrt(NOISE_PWR/2)
#define TWO_SUM_PROF 7.8179726742f         // 2 * sum_{j=0}^{7} exp(-j/4)

__device__ __forceinline__ float2 shflx(float2 v, int mask) {
    return make_float2(__shfl_xor(v.x, mask), __shfl_xor(v.y, mask));
}

// 64-point FFT across the 64 lanes of a wave, radix-2 DIF.
// Input: lane j holds x[j] (natural order).
// Output: lane j holds X[bitrev6(j)].
// tw[s] = per-lane stage twiddle with FORWARD sign (e^{-2pi i .../64}); (1,0) on lower lanes.
// DIR=0: forward FFT. DIR=1: inverse kernel (conjugated twiddles; NO 1/64 scale).
template<int DIR>
__device__ __forceinline__ float2 fft64(float2 v, const float2* tw, int lane) {
    #pragma unroll
    for (int s = 0; s < 6; ++s) {
        const int half = 32 >> s;
        float2 o = shflx(v, half);
        const bool up = (lane & half) != 0;
        // lower lane: a+b ; upper lane: (a-b) then twiddle
        float dx = up ? (o.x - v.x) : (o.x + v.x);
        float dy = up ? (o.y - v.y) : (o.y + v.y);
        float tx = tw[s].x;
        float ty = DIR ? -tw[s].y : tw[s].y;
        v.x = dx * tx - dy * ty;
        v.y = dx * ty + dy * tx;
    }
    return v;
}

__global__ __launch_bounds__(256) void ofdm_kernel(
    const float2* __restrict__ x,          // (NP, S, M)
    const float2* __restrict__ pilot_raw,  // (NP, M)
    const float2* __restrict__ cof_unit,   // (NP, L)
    const float2* __restrict__ noise_unit, // (NP, NSYM, MKK)
    float2* __restrict__ out_pilot,        // (NP, M)
    float2* __restrict__ out_sig,          // (NP, S, M)
    float2* __restrict__ out_H,            // (NP, M)
    float*  __restrict__ out_scalar)
{
    const int b    = blockIdx.x;
    const int tid  = threadIdx.x;
    const int wid  = tid >> 6;
    const int lane = tid & 63;

    __shared__ float2 sig[SMK];     // serialized time signal with CP
    __shared__ float2 z[NITEMS];    // post-channel samples (CP stripped), natural order
    __shared__ float2 cofs[LL];

    const float2* xb = x          + (size_t)b * (SS*MM);
    const float2* pb = pilot_raw  + (size_t)b * MM;
    const float2* cb = cof_unit   + (size_t)b * LL;
    const float2* nb = noise_unit + (size_t)b * (NSYM*MKK);

    // --- channel tap coefficients -> LDS (consumed by FIR after barrier 1) ---
    if (tid < LL) {
        float sc = sqrtf(__expf(-(float)tid * 0.25f) * (1.0f / TWO_SUM_PROF));
        float2 u = cb[tid];
        cofs[tid] = make_float2(sc * u.x, sc * u.y);
    }

    // --- per-lane stage twiddles (forward sign), kept in registers ---
    float2 twid[6];
    #pragma unroll
    for (int s = 0; s < 6; ++s) {
        const int half = 32 >> s;
        const int m = lane & (half - 1);
        float ang = -6.2831853071795864769f * (float)(m << s) * (1.0f / 64.0f);
        float sn, cs;
        __sincosf(ang, &sn, &cs);
        twid[s] = (lane & half) ? make_float2(cs, sn) : make_float2(1.0f, 0.0f);
    }

    const int rb = (int)(__brev((unsigned)lane) >> 26);   // bitrev6(lane)

    // --- pilot normalization (wave 0 only; wave-uniform after butterfly reduce) ---
    float alpha = 0.0f;
    float2 pv = make_float2(0.f, 0.f);
    if (wid == 0) {
        pv = pb[lane];
        float ss = pv.x * pv.x + pv.y * pv.y;
        #pragma unroll
        for (int off = 32; off > 0; off >>= 1)
            ss += __shfl_xor(ss, off);
        alpha = sqrtf(64.0f / ss);   // = sqrt(PWR/2)/sqrt(mean(pilot^2))
    }

    // --- Phase A: IFFT each owned symbol; write time signal with CP to LDS ---
    for (int sym = wid; sym < NSYM; sym += 4) {
        float2 v;
        if (sym == 0) v = make_float2(alpha * pv.x, alpha * pv.y);
        else          v = xb[(sym - 1) * MM + lane];
        v = fft64<1>(v, twid, lane);
        v.x *= (1.0f / 64.0f);
        v.y *= (1.0f / 64.0f);
        const int n = rb;                       // time index (bit-reversed lane)
        sig[sym * MKK + KK + n] = v;
        if (n >= MM - KK) sig[sym * MKK + n - (MM - KK)] = v;   // cyclic prefix
    }

    // --- H_true = FFT64 of zero-padded taps (wave 1; no LDS dependency) ---
    if (wid == 1) {
        float2 h = make_float2(0.f, 0.f);
        if (lane < LL) {
            float sc = sqrtf(__expf(-(float)lane * 0.25f) * (1.0f / TWO_SUM_PROF));
            float2 u = cb[lane];
            h = make_float2(sc * u.x, sc * u.y);
        }
        h = fft64<0>(h, twid, lane);
        out_H[(size_t)b * MM + rb] = h;
    }

    __syncthreads();

    // --- Phase B: 8-tap FIR + AWGN, CP stripped ---
    for (int i = tid; i < NITEMS; i += 256) {
        const int s = i >> 6, m = i & 63;
        const int pos = s * MKK + KK + m;
        float2 acc = make_float2(0.f, 0.f);
        #pragma unroll
        for (int t = 0; t < LL; ++t) {
            float2 c = cofs[t];
            float2 v = sig[pos - t];
            acc.x += c.x * v.x - c.y * v.y;
            acc.y += c.x * v.y + c.y * v.x;
        }
        float2 nu = nb[pos];
        acc.x += NOISE_SCALE * nu.x;
        acc.y += NOISE_SCALE * nu.y;
        z[i] = acc;
    }

    __syncthreads();

    // --- Phase C: forward FFT back to frequency domain; write outputs ---
    for (int sym = wid; sym < NSYM; sym += 4) {
        float2 v = z[sym * MM + lane];
        v = fft64<0>(v, twid, lane);
        if (sym == 0) out_pilot[(size_t)b * MM + rb] = v;
        else          out_sig[(size_t)b * (SS*MM) + (sym - 1) * MM + rb] = v;
    }

    if (b == 0 && tid == 0) out_scalar[0] = NOISE_PWR;
}

extern "C" void kernel_launch(void* const* d_in, const int* in_sizes, int n_in,
                              void* d_out, int out_size, void* d_ws, size_t ws_size,
                              hipStream_t stream) {
    const float2* x  = (const float2*)d_in[0];
    const float2* pr = (const float2*)d_in[1];
    const float2* cu = (const float2*)d_in[2];
    const float2* nu = (const float2*)d_in[3];

    float* out = (float*)d_out;
    float2* out_pilot = (float2*)(out + OFF_PILOT);
    float2* out_sig   = (float2*)(out + OFF_SIG);
    float2* out_H     = (float2*)(out + OFF_H);
    float*  out_sc    = out + OFF_SCALAR;

    ofdm_kernel<<<dim3(NN*PP), dim3(256), 0, stream>>>(
        x, pr, cu, nu, out_pilot, out_sig, out_H, out_sc);
}

// Round 3
// 120.737 us; speedup vs baseline: 2.9558x; 1.0583x over previous
//
#include <hip/hip_runtime.h>
#include <math.h>

// Problem constants
#define NN   1024
#define PP   4
#define SS   12
#define MM   64
#define KK   16
#define LL   8
#define MKK  80          // M + K
#define NSYM 13          // S + 1
#define SMK  1040        // NSYM * MKK

// Output layout (float element offsets in d_out)
#define OFF_PILOT  0
#define OFF_SIG    524288      // N*P*1*M*2
#define OFF_H      6815744     // + N*P*S*M*2
#define OFF_SCALAR 7340032     // + N*P*M*2

#define NOISE_PWR   1.5625e-4f             // PWR/(M*10^(0.1*SNR)) = 1/6400
#define NOISE_SCALE 8.8388347648318447e-3f // sqrt(NOISE_PWR/2)
#define INV_2SUM    0.1279105570f          // 1 / (2 * sum_{j<8} exp(-j/4))

__device__ __forceinline__ float2 shflx(float2 v, int mask) {
    return make_float2(__shfl_xor(v.x, mask), __shfl_xor(v.y, mask));
}

// Shared per-lane stage twiddles tw[s] (h = 1<<s): upper lanes (lane & h):
// exp(-2*pi*i*(lane&(h-1))/(2h)); lower lanes (1,0). sgn[s] = upper ? -1 : +1.
// DIF uses tw in order s=5..0 (natural in -> bitrev out);
// DIT uses tw in order s=0..5 (bitrev in -> natural out). Same table.

// DIF, natural in -> bitrev out. CONJ=1: inverse kernel (no 1/64 scale).
template<int CONJ, int NS>
__device__ __forceinline__ void fft64_dif(float2* v, const float2* tw, const float* sgn) {
    #pragma unroll
    for (int s = 5; s >= 0; --s) {
        float2 o[NS];
        #pragma unroll
        for (int j = 0; j < NS; ++j) o[j] = shflx(v[j], 1 << s);
        const float sg = sgn[s], tx = tw[s].x;
        const float ty = CONJ ? -tw[s].y : tw[s].y;
        #pragma unroll
        for (int j = 0; j < NS; ++j) {
            float dx = fmaf(sg, v[j].x, o[j].x);
            float dy = fmaf(sg, v[j].y, o[j].y);
            v[j].x = dx * tx - dy * ty;
            v[j].y = dx * ty + dy * tx;
        }
    }
}

// DIT, bitrev in -> natural out, forward sign.
template<int NS>
__device__ __forceinline__ void fft64_dit(float2* v, const float2* tw, const float* sgn) {
    #pragma unroll
    for (int s = 0; s < 6; ++s) {
        const float sg = sgn[s], tx = tw[s].x, ty = tw[s].y;
        float ax[NS], ay[NS];
        #pragma unroll
        for (int j = 0; j < NS; ++j) {
            ax[j] = v[j].x * tx - v[j].y * ty;
            ay[j] = v[j].x * ty + v[j].y * tx;
        }
        float2 o[NS];
        #pragma unroll
        for (int j = 0; j < NS; ++j) o[j] = shflx(make_float2(ax[j], ay[j]), 1 << s);
        #pragma unroll
        for (int j = 0; j < NS; ++j) {
            v[j].x = fmaf(sg, ax[j], o[j].x);
            v[j].y = fmaf(sg, ay[j], o[j].y);
        }
    }
}

__global__ __launch_bounds__(256) void ofdm_kernel(
    const float2* __restrict__ x,          // (NP, S, M)
    const float2* __restrict__ pilot_raw,  // (NP, M)
    const float2* __restrict__ cof_unit,   // (NP, L)
    const float2* __restrict__ noise_unit, // (NP, NSYM, MKK)
    float2* __restrict__ out_pilot,        // (NP, M)
    float2* __restrict__ out_sig,          // (NP, S, M)
    float2* __restrict__ out_H,            // (NP, M)
    float*  __restrict__ out_scalar)
{
    const int b    = blockIdx.x;
    const int tid  = threadIdx.x;
    const int wid  = tid >> 6;
    const int lane = tid & 63;

    __shared__ float2 sig[SMK];   // serialized time signal with CP

    const float2* xb = x          + (size_t)b * (SS*MM);
    const float2* pb = pilot_raw  + (size_t)b * MM;
    const float2* cb = cof_unit   + (size_t)b * LL;
    const float2* nb = noise_unit + (size_t)b * (NSYM*MKK);

    // --- per-lane stage twiddles + butterfly signs (registers) ---
    float2 tw[6];
    float  sgn[6];
    #pragma unroll
    for (int s = 0; s < 6; ++s) {
        const int h = 1 << s;
        const bool up = (lane & h) != 0;
        sgn[s] = up ? -1.0f : 1.0f;
        float ang = -6.2831853071795864769f * (float)(lane & (h - 1)) / (float)(2 * h);
        float sn, cs;
        __sincosf(ang, &sn, &cs);
        tw[s] = up ? make_float2(cs, sn) : make_float2(1.0f, 0.0f);
    }
    const int rb = (int)(__brev((unsigned)lane) >> 26);   // bitrev6(lane)

    // --- channel taps in registers (block-uniform loads) ---
    float2 cof[LL];
    #pragma unroll
    for (int t = 0; t < LL; ++t) {
        float sc = sqrtf(__expf(-(float)t * 0.25f) * INV_2SUM);
        float2 u = cb[t];
        cof[t] = make_float2(sc * u.x, sc * u.y);
    }

    // --- Phase A: IFFT owned symbols (interleaved chains), write sig+CP ---
    auto store_sig = [&](int sym, float2 vv) {
        vv.x *= (1.0f / 64.0f);
        vv.y *= (1.0f / 64.0f);
        sig[sym * MKK + KK + rb] = vv;
        if (rb >= MM - KK) sig[sym * MKK + rb - (MM - KK)] = vv;  // cyclic prefix
    };

    if (wid == 0) {
        float2 v[4];
        float2 pv = pb[lane];
        v[1] = xb[3 * MM + lane];    // sym 4
        v[2] = xb[7 * MM + lane];    // sym 8
        v[3] = xb[11 * MM + lane];   // sym 12
        float ssq = pv.x * pv.x + pv.y * pv.y;
        #pragma unroll
        for (int off = 32; off > 0; off >>= 1)
            ssq += __shfl_xor(ssq, off);
        float alpha = sqrtf(64.0f / ssq);   // sqrt(PWR/2)/sqrt(mean(pilot^2))
        v[0] = make_float2(alpha * pv.x, alpha * pv.y);
        fft64_dif<1, 4>(v, tw, sgn);
        store_sig(0, v[0]); store_sig(4, v[1]); store_sig(8, v[2]); store_sig(12, v[3]);
    } else {
        float2 v[3];
        v[0] = xb[(wid - 1) * MM + lane];   // sym wid
        v[1] = xb[(wid + 3) * MM + lane];   // sym wid+4
        v[2] = xb[(wid + 7) * MM + lane];   // sym wid+8
        fft64_dif<1, 3>(v, tw, sgn);
        store_sig(wid, v[0]); store_sig(wid + 4, v[1]); store_sig(wid + 8, v[2]);
    }

    __syncthreads();

    // --- Phase B+C fused: FIR + AWGN gathered at bitrev positions, DIT FFT,
    //     natural-order coalesced stores ---
    auto fir = [&](int sym) -> float2 {
        const int pos = sym * MKK + KK + rb;
        float2 nu = nb[pos];
        float2 acc = make_float2(NOISE_SCALE * nu.x, NOISE_SCALE * nu.y);
        #pragma unroll
        for (int t = 0; t < LL; ++t) {
            float2 c = cof[t];
            float2 s2 = sig[pos - t];
            acc.x += c.x * s2.x - c.y * s2.y;
            acc.y += c.x * s2.y + c.y * s2.x;
        }
        return acc;
    };

    const size_t ob = (size_t)b * MM;
    const size_t osb = (size_t)b * (SS * MM);

    if (wid <= 1) {
        float2 v[4];
        v[0] = fir(wid);
        v[1] = fir(wid + 4);
        v[2] = fir(wid + 8);
        if (wid == 0) {
            v[3] = fir(12);
        } else {
            float2 h = make_float2(0.0f, 0.0f);
            if (rb < LL) {
                float sc = sqrtf(__expf(-(float)rb * 0.25f) * INV_2SUM);
                float2 u = cb[rb];
                h = make_float2(sc * u.x, sc * u.y);
            }
            v[3] = h;   // H_true input, bitrev order
        }
        fft64_dit<4>(v, tw, sgn);
        if (wid == 0) {
            out_pilot[ob + lane]            = v[0];
            out_sig[osb + 3 * MM + lane]    = v[1];   // sym 4
            out_sig[osb + 7 * MM + lane]    = v[2];   // sym 8
            out_sig[osb + 11 * MM + lane]   = v[3];   // sym 12
        } else {
            out_sig[osb + 0 * MM + lane]    = v[0];   // sym 1
            out_sig[osb + 4 * MM + lane]    = v[1];   // sym 5
            out_sig[osb + 8 * MM + lane]    = v[2];   // sym 9
            out_H[ob + lane]                = v[3];
        }
    } else {
        float2 v[3];
        v[0] = fir(wid);
        v[1] = fir(wid + 4);
        v[2] = fir(wid + 8);
        fft64_dit<3>(v, tw, sgn);
        out_sig[osb + (wid - 1) * MM + lane] = v[0];
        out_sig[osb + (wid + 3) * MM + lane] = v[1];
        out_sig[osb + (wid + 7) * MM + lane] = v[2];
    }

    if (b == 0 && tid == 0) out_scalar[0] = NOISE_PWR;
}

extern "C" void kernel_launch(void* const* d_in, const int* in_sizes, int n_in,
                              void* d_out, int out_size, void* d_ws, size_t ws_size,
                              hipStream_t stream) {
    const float2* x  = (const float2*)d_in[0];
    const float2* pr = (const float2*)d_in[1];
    const float2* cu = (const float2*)d_in[2];
    const float2* nu = (const float2*)d_in[3];

    float* out = (float*)d_out;
    float2* out_pilot = (float2*)(out + OFF_PILOT);
    float2* out_sig   = (float2*)(out + OFF_SIG);
    float2* out_H     = (float2*)(out + OFF_H);
    float*  out_sc    = out + OFF_SCALAR;

    ofdm_kernel<<<dim3(NN*PP), dim3(256), 0, stream>>>(
        x, pr, cu, nu, out_pilot, out_sig, out_H, out_sc);
}

// Round 4
// 106.148 us; speedup vs baseline: 3.3620x; 1.1374x over previous
//
#include <hip/hip_runtime.h>
#include <math.h>

// Problem constants
#define NN   1024
#define PP   4
#define SS   12
#define MM   64
#define KK   16
#define LL   8
#define MKK  80          // M + K
#define NSYM 13          // S + 1

// Output layout (float element offsets in d_out)
#define OFF_PILOT  0
#define OFF_SIG    524288      // N*P*1*M*2
#define OFF_H      6815744     // + N*P*S*M*2
#define OFF_SCALAR 7340032     // + N*P*M*2

#define NOISE_PWR   1.5625e-4f             // PWR/(M*10^(0.1*SNR)) = 1/6400
#define NOISE_SCALE 8.8388347648318447e-3f // sqrt(NOISE_PWR/2)
#define INV_2SUM    0.1279105570f          // 1 / (2 * sum_{j<8} exp(-j/4))

// ALGEBRAIC IDENTITY used here: CP length (K=16) >= channel length (L=8), so
// the linear convolution restricted to the CP-stripped window of each symbol
// is exactly a 64-pt circular convolution of that symbol's time signal.
// FFT(IFFT(X)) = X  =>  info[s,k] = H64[k]*X[s,k] + NOISE_SCALE*FFT64(noise[s,K:])[k].
// Only the noise FFTs remain; no IFFT, no FIR, no LDS, no barriers.

__device__ __forceinline__ float2 shflx(float2 v, int mask) {
    return make_float2(__shfl_xor(v.x, mask), __shfl_xor(v.y, mask));
}
__device__ __forceinline__ float2 cmul(float2 a, float2 b) {
    return make_float2(a.x*b.x - a.y*b.y, a.x*b.y + a.y*b.x);
}

// DIT radix-2 across 64 lanes: bitrev-order in -> natural-order out, forward sign.
// tw[s] (h=1<<s): upper lanes (lane&h) hold exp(-2*pi*i*(lane&(h-1))/(2h)), lower (1,0).
template<int NS>
__device__ __forceinline__ void fft64_dit(float2* v, const float2* tw, const float* sgn) {
    #pragma unroll
    for (int s = 0; s < 6; ++s) {
        const float sg = sgn[s], tx = tw[s].x, ty = tw[s].y;
        float ax[NS], ay[NS];
        #pragma unroll
        for (int j = 0; j < NS; ++j) {
            ax[j] = v[j].x * tx - v[j].y * ty;
            ay[j] = v[j].x * ty + v[j].y * tx;
        }
        float2 o[NS];
        #pragma unroll
        for (int j = 0; j < NS; ++j) o[j] = shflx(make_float2(ax[j], ay[j]), 1 << s);
        #pragma unroll
        for (int j = 0; j < NS; ++j) {
            v[j].x = fmaf(sg, ax[j], o[j].x);
            v[j].y = fmaf(sg, ay[j], o[j].y);
        }
    }
}

__global__ __launch_bounds__(256) void ofdm_kernel(
    const float2* __restrict__ x,          // (NP, S, M)
    const float2* __restrict__ pilot_raw,  // (NP, M)
    const float2* __restrict__ cof_unit,   // (NP, L)
    const float2* __restrict__ noise_unit, // (NP, NSYM, MKK)
    float2* __restrict__ out_pilot,        // (NP, M)
    float2* __restrict__ out_sig,          // (NP, S, M)
    float2* __restrict__ out_H,            // (NP, M)
    float*  __restrict__ out_scalar)
{
    const int b    = blockIdx.x;
    const int tid  = threadIdx.x;
    const int wid  = tid >> 6;
    const int lane = tid & 63;

    const float2* xb = x          + (size_t)b * (SS*MM);
    const float2* pb = pilot_raw  + (size_t)b * MM;
    const float2* cb = cof_unit   + (size_t)b * LL;
    const float2* nb = noise_unit + (size_t)b * (NSYM*MKK);

    const int rb = (int)(__brev((unsigned)lane) >> 26);   // bitrev6(lane)

    // --- channel taps (block-uniform loads), issued first ---
    float2 cof[LL];
    #pragma unroll
    for (int t = 0; t < LL; ++t) {
        float2 u = cb[t];
        float sc = sqrtf(__expf(-(float)t * 0.25f) * INV_2SUM);
        cof[t] = make_float2(sc * u.x, sc * u.y);
    }

    // --- per-lane stage twiddles + butterfly signs (registers, forward sign) ---
    float2 tw[6];
    float  sgn[6];
    #pragma unroll
    for (int s = 0; s < 6; ++s) {
        const int h = 1 << s;
        const bool up = (lane & h) != 0;
        sgn[s] = up ? -1.0f : 1.0f;
        float ang = -6.2831853071795864769f * (float)(lane & (h - 1)) / (float)(2 * h);
        float sn, cs;
        __sincosf(ang, &sn, &cs);
        tw[s] = up ? make_float2(cs, sn) : make_float2(1.0f, 0.0f);
    }

    // --- H64[lane] = sum_{l<8} cof[l] * w^l,  w = exp(-2*pi*i*lane/64), via Horner ---
    float sn, cs;
    __sincosf(-0.0981747704246810387f * (float)lane, &sn, &cs);
    const float2 w = make_float2(cs, sn);
    float2 H = cof[LL - 1];
    #pragma unroll
    for (int l = LL - 2; l >= 0; --l) {
        float2 Hw = cmul(H, w);
        H = make_float2(Hw.x + cof[l].x, Hw.y + cof[l].y);
    }

    const size_t ob  = (size_t)b * MM;
    const size_t osb = (size_t)b * (SS * MM);

    if (wid == 1) out_H[ob + lane] = H;   // natural order, coalesced

    if (wid == 0) {
        // symbols 0 (pilot), 4, 8, 12
        float2 nv[4];
        nv[0] = nb[ 0*MKK + KK + rb];
        nv[1] = nb[ 4*MKK + KK + rb];
        nv[2] = nb[ 8*MKK + KK + rb];
        nv[3] = nb[12*MKK + KK + rb];
        float2 pv = pb[lane];
        float2 X1 = xb[ 3*MM + lane];
        float2 X2 = xb[ 7*MM + lane];
        float2 X3 = xb[11*MM + lane];
        #pragma unroll
        for (int j = 0; j < 4; ++j) {
            nv[j].x *= NOISE_SCALE; nv[j].y *= NOISE_SCALE;
        }
        fft64_dit<4>(nv, tw, sgn);

        float ssq = pv.x * pv.x + pv.y * pv.y;
        #pragma unroll
        for (int off = 32; off > 0; off >>= 1)
            ssq += __shfl_xor(ssq, off);
        float alpha = sqrtf(64.0f / ssq);   // sqrt(PWR/2)/sqrt(mean(pilot_raw^2))
        float2 X0 = make_float2(alpha * pv.x, alpha * pv.y);

        float2 o0 = cmul(H, X0), o1 = cmul(H, X1), o2 = cmul(H, X2), o3 = cmul(H, X3);
        out_pilot[ob + lane]          = make_float2(o0.x + nv[0].x, o0.y + nv[0].y);
        out_sig[osb +  3*MM + lane]   = make_float2(o1.x + nv[1].x, o1.y + nv[1].y);
        out_sig[osb +  7*MM + lane]   = make_float2(o2.x + nv[2].x, o2.y + nv[2].y);
        out_sig[osb + 11*MM + lane]   = make_float2(o3.x + nv[3].x, o3.y + nv[3].y);
    } else {
        // symbols wid, wid+4, wid+8  (payload indices wid-1, wid+3, wid+7)
        float2 nv[3];
        nv[0] = nb[(wid    ) * MKK + KK + rb];
        nv[1] = nb[(wid + 4) * MKK + KK + rb];
        nv[2] = nb[(wid + 8) * MKK + KK + rb];
        float2 X0 = xb[(wid - 1) * MM + lane];
        float2 X1 = xb[(wid + 3) * MM + lane];
        float2 X2 = xb[(wid + 7) * MM + lane];
        #pragma unroll
        for (int j = 0; j < 3; ++j) {
            nv[j].x *= NOISE_SCALE; nv[j].y *= NOISE_SCALE;
        }
        fft64_dit<3>(nv, tw, sgn);

        float2 o0 = cmul(H, X0), o1 = cmul(H, X1), o2 = cmul(H, X2);
        out_sig[osb + (wid - 1) * MM + lane] = make_float2(o0.x + nv[0].x, o0.y + nv[0].y);
        out_sig[osb + (wid + 3) * MM + lane] = make_float2(o1.x + nv[1].x, o1.y + nv[1].y);
        out_sig[osb + (wid + 7) * MM + lane] = make_float2(o2.x + nv[2].x, o2.y + nv[2].y);
    }

    if (b == 0 && tid == 0) out_scalar[0] = NOISE_PWR;
}

extern "C" void kernel_launch(void* const* d_in, const int* in_sizes, int n_in,
                              void* d_out, int out_size, void* d_ws, size_t ws_size,
                              hipStream_t stream) {
    const float2* x  = (const float2*)d_in[0];
    const float2* pr = (const float2*)d_in[1];
    const float2* cu = (const float2*)d_in[2];
    const float2* nu = (const float2*)d_in[3];

    float* out = (float*)d_out;
    float2* out_pilot = (float2*)(out + OFF_PILOT);
    float2* out_sig   = (float2*)(out + OFF_SIG);
    float2* out_H     = (float2*)(out + OFF_H);
    float*  out_sc    = out + OFF_SCALAR;

    ofdm_kernel<<<dim3(NN*PP), dim3(256), 0, stream>>>(
        x, pr, cu, nu, out_pilot, out_sig, out_H, out_sc);
}